// Round 2
// baseline (1033.025 us; speedup 1.0000x reference)
//
#include <hip/hip_runtime.h>
#include <hip/hip_bf16.h>

#define NN 100000
#define DD 128
#define RR 8
#define EE 100000

typedef __attribute__((ext_vector_type(8))) short short8;
typedef __attribute__((ext_vector_type(4))) float f32x4;

__device__ __forceinline__ unsigned short f2bf(float v) {
  union { float f; unsigned int u; } x; x.f = v;
  unsigned int r = (x.u + 0x7FFFu + ((x.u >> 16) & 1u)) >> 16;
  return (unsigned short)r;
}

// ---- cast f32 -> bf16, 4 elems/thread, grid-stride
__global__ void k_cast4(const float* __restrict__ src, unsigned short* __restrict__ dst, int n4) {
  int i = blockIdx.x * blockDim.x + threadIdx.x;
  int stride = gridDim.x * blockDim.x;
  for (; i < n4; i += stride) {
    float4 v = reinterpret_cast<const float4*>(src)[i];
    ushort4 o;
    o.x = f2bf(v.x); o.y = f2bf(v.y); o.z = f2bf(v.z); o.w = f2bf(v.w);
    reinterpret_cast<ushort4*>(dst)[i] = o;
  }
}

// ---- cast + transpose weights: src[r][k][o] f32 -> dst[r][o][k] bf16
__global__ void k_castT(const float* __restrict__ src, unsigned short* __restrict__ dst, int total) {
  int i = blockIdx.x * blockDim.x + threadIdx.x;
  if (i >= total) return;
  int r = i >> 14;
  int k = (i >> 7) & 127;
  int o = i & 127;
  dst[(r << 14) + (o << 7) + k] = f2bf(src[i]);
}

__global__ void k_zero(unsigned int* __restrict__ p, int n) {
  int i = blockIdx.x * blockDim.x + threadIdx.x;
  if (i < n) p[i] = 0u;
}

// ---- mask[r][n] = 1 if n is a target of relation r
__global__ void k_mask(const int* __restrict__ edge_index, unsigned char* __restrict__ mask) {
  int e = blockIdx.x * blockDim.x + threadIdx.x;
  int r = blockIdx.y;
  if (e >= EE) return;
  int tgt = edge_index[(size_t)r * 2 * EE + EE + e];
  mask[(size_t)r * NN + tgt] = 1;
}

// ================= counting sort of edges by target (per relation) =============

__global__ void k_hist(const int* __restrict__ edge_index, int* __restrict__ cnt) {
  int e = blockIdx.x * blockDim.x + threadIdx.x;
  int r = blockIdx.y;
  if (e >= EE) return;
  int tgt = edge_index[(size_t)r * 2 * EE + EE + e];
  atomicAdd(&cnt[r * NN + tgt], 1);
}

// one block (1024 thr) per relation: exclusive prefix over NN bins
__global__ void k_scan(const int* __restrict__ cnt, int* __restrict__ start) {
  const int r = blockIdx.x;
  const int t = threadIdx.x;
  const int CH = (NN + 1023) / 1024;  // 98
  const int base = r * NN;
  int lo = t * CH;
  int hi = lo + CH; if (hi > NN) hi = NN;
  int s = 0;
  for (int i = lo; i < hi; ++i) s += cnt[base + i];
  __shared__ int sums[1024];
  sums[t] = s;
  __syncthreads();
  for (int off = 1; off < 1024; off <<= 1) {
    int u = (t >= off) ? sums[t - off] : 0;
    __syncthreads();
    sums[t] += u;
    __syncthreads();
  }
  int run = sums[t] - s;  // exclusive prefix of this chunk
  for (int i = lo; i < hi; ++i) { start[base + i] = run; run += cnt[base + i]; }
}

// scatter-permute: sidx[r][pos] = e, pos = cursor[r][tgt]++  (destroys cursor)
__global__ void k_scatter_sort(const int* __restrict__ edge_index, int* __restrict__ cursor,
                               int* __restrict__ sidx) {
  int e = blockIdx.x * blockDim.x + threadIdx.x;
  int r = blockIdx.y;
  if (e >= EE) return;
  int tgt = edge_index[(size_t)r * 2 * EE + EE + e];
  int pos = atomicAdd(&cursor[r * NN + tgt], 1);
  sidx[r * EE + pos] = e;
}

// ================= GEMM kernels =================
// LDS tiles 128x128 bf16, chunk-XOR swizzle: chunk kc (8 bf16 = 16B) of row R
// stored at element (R<<7) + ((kc ^ (R&7))<<3). Keeps ds_*_b128 bank-uniform.

__device__ __forceinline__ void stage_B(const unsigned short* __restrict__ Wt,
                                        unsigned short* __restrict__ lB, int t) {
#pragma unroll
  for (int c = 0; c < 8; ++c) {
    int g = t + 256 * c;
    int o = g >> 4, kc = g & 15;
    int4 v = *reinterpret_cast<const int4*>(Wt + (o << 7) + (kc << 3));
    *reinterpret_cast<int4*>(&lB[(o << 7) + ((kc ^ (o & 7)) << 3)]) = v;
  }
}

__device__ __forceinline__ void stage_A_row(const unsigned short* __restrict__ gp,
                                            unsigned short* __restrict__ lA,
                                            int lr, int half) {
#pragma unroll
  for (int c = 0; c < 8; ++c) {
    int kc = half * 8 + c;
    int4 v = *reinterpret_cast<const int4*>(gp + (kc << 3));
    *reinterpret_cast<int4*>(&lA[(lr << 7) + ((kc ^ (lr & 7)) << 3)]) = v;
  }
}

#define MFMA_BODY                                                                     \
  const int w = t >> 6, l = t & 63;                                                   \
  const int lrow = l & 15, kgrp = l >> 4;                                             \
  f32x4 acc[2][8] = {};                                                               \
  _Pragma("unroll")                                                                   \
  for (int ks = 0; ks < 4; ++ks) {                                                    \
    int kc = ks * 4 + kgrp;                                                           \
    int ra = w * 32 + lrow;                                                           \
    int rb = ra + 16;                                                                 \
    short8 a0 = *reinterpret_cast<const short8*>(&lA[(ra << 7) + ((kc ^ (ra & 7)) << 3)]); \
    short8 a1 = *reinterpret_cast<const short8*>(&lA[(rb << 7) + ((kc ^ (rb & 7)) << 3)]); \
    _Pragma("unroll")                                                                 \
    for (int ct = 0; ct < 8; ++ct) {                                                  \
      int ro = ct * 16 + lrow;                                                        \
      short8 b = *reinterpret_cast<const short8*>(&lB[(ro << 7) + ((kc ^ (ro & 7)) << 3)]); \
      acc[0][ct] = __builtin_amdgcn_mfma_f32_16x16x32_bf16(a0, b, acc[0][ct], 0, 0, 0);    \
      acc[1][ct] = __builtin_amdgcn_mfma_f32_16x16x32_bf16(a1, b, acc[1][ct], 0, 0, 0);    \
    }                                                                                 \
  }

// out[row,:] = Xb[row,:] @ W  (W given pre-transposed [o][k]); non-atomic init write
__launch_bounds__(256, 2)
__global__ void k_gemm_self(const unsigned short* __restrict__ Xb,
                            const unsigned short* __restrict__ Wt,
                            float* __restrict__ out) {
  __shared__ __align__(16) unsigned short lA[128 * 128];
  __shared__ __align__(16) unsigned short lB[128 * 128];
  const int t = threadIdx.x;
  const int row0 = blockIdx.x * 128;

  stage_B(Wt, lB, t);
  {
    int lr = t >> 1, half = t & 1;
    int grow = row0 + lr;
    int sr = grow < NN ? grow : 0;
    stage_A_row(Xb + (size_t)sr * 128, lA, lr, half);
  }
  __syncthreads();

  MFMA_BODY

#pragma unroll
  for (int rt = 0; rt < 2; ++rt) {
#pragma unroll
    for (int j = 0; j < 4; ++j) {
      int grow = row0 + w * 32 + rt * 16 + kgrp * 4 + j;
      if (grow < NN) {
        float* op = out + (size_t)grow * 128 + lrow;
#pragma unroll
        for (int ct = 0; ct < 8; ++ct) op[ct * 16] = acc[rt][ct][j];
      }
    }
  }
}

// per-edge (target-sorted order): agg[tgt[e],:] += w[e]*(Xb[src[e],:] @ relW[r])
__launch_bounds__(256, 2)
__global__ void k_gemm_edge(const unsigned short* __restrict__ Xb,
                            const unsigned short* __restrict__ Wt_all,
                            const int* __restrict__ edge_index,
                            const float* __restrict__ ew,
                            const int* __restrict__ sidx,
                            float* __restrict__ agg) {
  __shared__ __align__(16) unsigned short lA[128 * 128];
  __shared__ __align__(16) unsigned short lB[128 * 128];
  const int t = threadIdx.x;
  const int r = blockIdx.y;
  const int e0 = blockIdx.x * 128;
  const int* src_p = edge_index + (size_t)r * 2 * EE;
  const int* tgt_p = src_p + EE;
  const float* w_p = ew + (size_t)r * EE;
  const int* sx = sidx + (size_t)r * EE;

  stage_B(Wt_all + (r << 14), lB, t);
  {
    int lr = t >> 1, half = t & 1;
    int e = e0 + lr;
    int ei = (e < EE) ? sx[e] : 0;
    int s = (e < EE) ? src_p[ei] : 0;
    stage_A_row(Xb + (size_t)s * 128, lA, lr, half);
  }
  __syncthreads();

  MFMA_BODY

#pragma unroll
  for (int rt = 0; rt < 2; ++rt) {
#pragma unroll
    for (int j = 0; j < 4; ++j) {
      int lr2 = w * 32 + rt * 16 + kgrp * 4 + j;
      int e2 = e0 + lr2;
      if (e2 < EE) {
        int ei2 = sx[e2];
        float wgt = w_p[ei2];
        int tg = tgt_p[ei2];
        float* op = agg + (size_t)tg * 128 + lrow;
#pragma unroll
        for (int ct = 0; ct < 8; ++ct)
          unsafeAtomicAdd(&op[ct * 16], wgt * acc[rt][ct][j]);
      }
    }
  }
}

// epilogue layer1: h_bf16 = bf16(relu(h32 + sum_r mask[r][n]*bias[r,:]))
__global__ void k_epi1(const float* __restrict__ h32, const unsigned char* __restrict__ mask,
                       const float* __restrict__ bias, unsigned short* __restrict__ hb) {
  int gid = blockIdx.x * blockDim.x + threadIdx.x;
  if (gid >= NN * 32) return;
  int n = gid >> 5, c = (gid & 31) << 2;
  float4 v = *reinterpret_cast<const float4*>(h32 + (size_t)n * 128 + c);
  float b0 = 0, b1 = 0, b2 = 0, b3 = 0;
#pragma unroll
  for (int r = 0; r < RR; ++r) {
    if (mask[(size_t)r * NN + n]) {
      const float* bp = bias + r * 128 + c;
      b0 += bp[0]; b1 += bp[1]; b2 += bp[2]; b3 += bp[3];
    }
  }
  ushort4 o;
  o.x = f2bf(fmaxf(v.x + b0, 0.f));
  o.y = f2bf(fmaxf(v.y + b1, 0.f));
  o.z = f2bf(fmaxf(v.z + b2, 0.f));
  o.w = f2bf(fmaxf(v.w + b3, 0.f));
  *reinterpret_cast<ushort4*>(hb + (size_t)n * 128 + c) = o;
}

// epilogue layer2: out += sum_r mask[r][n]*bias[r,:]  (in-place f32)
__global__ void k_epi2(float* __restrict__ out, const unsigned char* __restrict__ mask,
                       const float* __restrict__ bias) {
  int gid = blockIdx.x * blockDim.x + threadIdx.x;
  if (gid >= NN * 32) return;
  int n = gid >> 5, c = (gid & 31) << 2;
  float b0 = 0, b1 = 0, b2 = 0, b3 = 0;
  bool any = false;
#pragma unroll
  for (int r = 0; r < RR; ++r) {
    if (mask[(size_t)r * NN + n]) {
      any = true;
      const float* bp = bias + r * 128 + c;
      b0 += bp[0]; b1 += bp[1]; b2 += bp[2]; b3 += bp[3];
    }
  }
  if (any) {
    float* p = out + (size_t)n * 128 + c;
    float4 v = *reinterpret_cast<const float4*>(p);
    v.x += b0; v.y += b1; v.z += b2; v.w += b3;
    *reinterpret_cast<float4*>(p) = v;
  }
}

extern "C" void kernel_launch(void* const* d_in, const int* in_sizes, int n_in,
                              void* d_out, int out_size, void* d_ws, size_t ws_size,
                              hipStream_t stream) {
  const float* X   = (const float*)d_in[0];
  const int*   EI  = (const int*)d_in[1];
  const float* EW  = (const float*)d_in[2];
  const float* rW1 = (const float*)d_in[3];
  const float* sW1 = (const float*)d_in[4];
  const float* b1  = (const float*)d_in[5];
  const float* rW2 = (const float*)d_in[6];
  const float* sW2 = (const float*)d_in[7];
  const float* b2  = (const float*)d_in[8];
  float* out = (float*)d_out;
  char* ws = (char*)d_ws;

  size_t off = 0;
  auto take = [&](size_t sz) { char* p = ws + off; off += (sz + 255) & ~(size_t)255; return p; };
  unsigned short* Xb   = (unsigned short*)take((size_t)NN * DD * 2);
  unsigned short* hb   = (unsigned short*)take((size_t)NN * DD * 2);
  float*          h32  = (float*)take((size_t)NN * DD * 4);
  unsigned char*  mask = (unsigned char*)take((size_t)RR * NN);
  unsigned short* rW1t = (unsigned short*)take((size_t)RR * DD * DD * 2);
  unsigned short* sW1t = (unsigned short*)take((size_t)DD * DD * 2);
  unsigned short* rW2t = (unsigned short*)take((size_t)RR * DD * DD * 2);
  unsigned short* sW2t = (unsigned short*)take((size_t)DD * DD * 2);
  int* cnt   = (int*)take((size_t)RR * NN * 4);
  int* start = (int*)take((size_t)RR * NN * 4);
  int* sidx  = (int*)take((size_t)RR * EE * 4);

  // casts
  k_cast4<<<2048, 256, 0, stream>>>(X, Xb, NN * DD / 4);
  k_castT<<<(RR * DD * DD + 255) / 256, 256, 0, stream>>>(rW1, rW1t, RR * DD * DD);
  k_castT<<<(DD * DD + 255) / 256, 256, 0, stream>>>(sW1, sW1t, DD * DD);
  k_castT<<<(RR * DD * DD + 255) / 256, 256, 0, stream>>>(rW2, rW2t, RR * DD * DD);
  k_castT<<<(DD * DD + 255) / 256, 256, 0, stream>>>(sW2, sW2t, DD * DD);

  // target mask (shared by both layers)
  k_zero<<<(RR * NN / 4 + 255) / 256, 256, 0, stream>>>((unsigned int*)mask, RR * NN / 4);
  k_mask<<<dim3((EE + 255) / 256, RR), 256, 0, stream>>>(EI, mask);

  // counting sort of edges by target, per relation (reused by both layers)
  k_zero<<<(RR * NN + 255) / 256, 256, 0, stream>>>((unsigned int*)cnt, RR * NN);
  k_hist<<<dim3((EE + 255) / 256, RR), 256, 0, stream>>>(EI, cnt);
  k_scan<<<RR, 1024, 0, stream>>>(cnt, start);
  k_scatter_sort<<<dim3((EE + 255) / 256, RR), 256, 0, stream>>>(EI, start, sidx);

  const int nblk = (NN + 127) / 128;  // 782
  // ---- layer 1
  k_gemm_self<<<nblk, 256, 0, stream>>>(Xb, sW1t, h32);
  k_gemm_edge<<<dim3(nblk, RR), 256, 0, stream>>>(Xb, rW1t, EI, EW, sidx, h32);
  k_epi1<<<(NN * 32 + 255) / 256, 256, 0, stream>>>(h32, mask, b1, hb);
  // ---- layer 2
  k_gemm_self<<<nblk, 256, 0, stream>>>(hb, sW2t, out);
  k_gemm_edge<<<dim3(nblk, RR), 256, 0, stream>>>(hb, rW2t, EI, EW, sidx, out);
  k_epi2<<<(NN * 32 + 255) / 256, 256, 0, stream>>>(out, mask, b2);
}

// Round 3
// 713.326 us; speedup vs baseline: 1.4482x; 1.4482x over previous
//
#include <hip/hip_runtime.h>
#include <hip/hip_bf16.h>

#define NN 100000
#define DD 128
#define RR 8
#define EE 100000
#define NP1 (NN + 1)
#define NB1 98            // ceil(NN/1024)
#define PADN (NB1 * 1024) // 100352, padded bins per relation

typedef __attribute__((ext_vector_type(8))) short short8;
typedef __attribute__((ext_vector_type(4))) float f32x4;

__device__ __forceinline__ unsigned short f2bf(float v) {
  union { float f; unsigned int u; } x; x.f = v;
  unsigned int r = (x.u + 0x7FFFu + ((x.u >> 16) & 1u)) >> 16;
  return (unsigned short)r;
}

// ---- cast f32 -> bf16, 4 elems/thread, grid-stride
__global__ void k_cast4(const float* __restrict__ src, unsigned short* __restrict__ dst, int n4) {
  int i = blockIdx.x * blockDim.x + threadIdx.x;
  int stride = gridDim.x * blockDim.x;
  for (; i < n4; i += stride) {
    float4 v = reinterpret_cast<const float4*>(src)[i];
    ushort4 o;
    o.x = f2bf(v.x); o.y = f2bf(v.y); o.z = f2bf(v.z); o.w = f2bf(v.w);
    reinterpret_cast<ushort4*>(dst)[i] = o;
  }
}

// ---- cast + transpose weights: src[r][k][o] f32 -> dst[r][o][k] bf16
__global__ void k_castT(const float* __restrict__ src, unsigned short* __restrict__ dst, int total) {
  int i = blockIdx.x * blockDim.x + threadIdx.x;
  if (i >= total) return;
  int r = i >> 14;
  int k = (i >> 7) & 127;
  int o = i & 127;
  dst[(r << 14) + (o << 7) + k] = f2bf(src[i]);
}

__global__ void k_zero(unsigned int* __restrict__ p, int n) {
  int i = blockIdx.x * blockDim.x + threadIdx.x;
  if (i < n) p[i] = 0u;
}

// ---- mask[r][n] = 1 if n is a target of relation r
__global__ void k_mask(const int* __restrict__ edge_index, unsigned char* __restrict__ mask) {
  int e = blockIdx.x * blockDim.x + threadIdx.x;
  int r = blockIdx.y;
  if (e >= EE) return;
  int tgt = edge_index[(size_t)r * 2 * EE + EE + e];
  mask[(size_t)r * NN + tgt] = 1;
}

// ============== CSR build: counting sort of edges by target, per relation ======

__global__ void k_hist(const int* __restrict__ edge_index, int* __restrict__ cnt) {
  int e = blockIdx.x * blockDim.x + threadIdx.x;
  int r = blockIdx.y;
  if (e >= EE) return;
  int tgt = edge_index[(size_t)r * 2 * EE + EE + e];
  atomicAdd(&cnt[r * PADN + tgt], 1);
}

// level-1 scan: 1024 bins per block (4/thread), write per-block-exclusive starts + block sums
__global__ void k_scan1(const int* __restrict__ cnt, int* __restrict__ start, int* __restrict__ bsum) {
  const int r = blockIdx.y, b = blockIdx.x, t = threadIdx.x;
  const int bin0 = b * 1024 + t * 4;
  int4 c = *reinterpret_cast<const int4*>(&cnt[r * PADN + bin0]);
  int s1 = c.x, s2 = s1 + c.y, s3 = s2 + c.z, tot = s3 + c.w;
  __shared__ int sh[256];
  sh[t] = tot;
  __syncthreads();
  for (int off = 1; off < 256; off <<= 1) {
    int v = (t >= off) ? sh[t - off] : 0;
    __syncthreads();
    sh[t] += v;
    __syncthreads();
  }
  int excl = sh[t] - tot;
  if (t == 255) bsum[r * NB1 + b] = sh[255];
  const int base = r * NP1;
  if (bin0 < NN) start[base + bin0] = excl;
  if (bin0 + 1 < NN) start[base + bin0 + 1] = excl + s1;
  if (bin0 + 2 < NN) start[base + bin0 + 2] = excl + s2;
  if (bin0 + 3 < NN) start[base + bin0 + 3] = excl + s3;
}

// level-2: scan the 98 block sums per relation
__global__ void k_scan2(const int* __restrict__ bsum, int* __restrict__ boff, int* __restrict__ start) {
  const int r = blockIdx.x, t = threadIdx.x;
  int v = (t < NB1) ? bsum[r * NB1 + t] : 0;
  __shared__ int sh[128];
  sh[t] = v;
  __syncthreads();
  for (int off = 1; off < 128; off <<= 1) {
    int u = (t >= off) ? sh[t - off] : 0;
    __syncthreads();
    sh[t] += u;
    __syncthreads();
  }
  if (t < NB1) boff[r * NB1 + t] = sh[t] - v;
  if (t == 0) start[r * NP1 + NN] = EE;
}

// level-3: add block offsets; copy to cursor
__global__ void k_scan3(int* __restrict__ start, const int* __restrict__ boff, int* __restrict__ cursor) {
  const int r = blockIdx.y, b = blockIdx.x, t = threadIdx.x;
  const int bin0 = b * 1024 + t * 4;
  const int off = boff[r * NB1 + b];
  const int base = r * NP1;
#pragma unroll
  for (int k = 0; k < 4; ++k) {
    int bin = bin0 + k;
    if (bin < NN) {
      int v = start[base + bin] + off;
      start[base + bin] = v;
      cursor[r * NN + bin] = v;
    }
  }
}

// scatter: write src and weight in target-sorted position
__global__ void k_scatter2(const int* __restrict__ edge_index, const float* __restrict__ ew,
                           int* __restrict__ cursor, int* __restrict__ ssrc, float* __restrict__ sw) {
  int e = blockIdx.x * blockDim.x + threadIdx.x;
  int r = blockIdx.y;
  if (e >= EE) return;
  const int* src_p = edge_index + (size_t)r * 2 * EE;
  int tgt = src_p[EE + e];
  int pos = atomicAdd(&cursor[r * NN + tgt], 1);
  ssrc[r * EE + pos] = src_p[e];
  sw[r * EE + pos] = ew[(size_t)r * EE + e];
}

// ============== pre-aggregation: P_r[n][:] = sum_{e in seg(r,n)} w_e * X[src_e][:] ====
// one wave per (relation, target node); lane l owns feature dword l (2 bf16)
__global__ void k_preagg(const unsigned short* __restrict__ Xb,
                         const int* __restrict__ ssrc, const float* __restrict__ sw,
                         const int* __restrict__ start,
                         unsigned short* __restrict__ P0, unsigned short* __restrict__ P1,
                         unsigned short* __restrict__ P2,
                         int rbase, int nrel) {
  const int gid = blockIdx.x * 4 + (threadIdx.x >> 6);
  if (gid >= nrel * NN) return;
  const int lane = threadIdx.x & 63;
  const int rr = gid / NN;
  const int n = gid - rr * NN;
  const int r = rbase + rr;
  const int s0 = __builtin_amdgcn_readfirstlane(start[r * NP1 + n]);
  const int s1 = __builtin_amdgcn_readfirstlane(start[r * NP1 + n + 1]);
  const unsigned int* Xu = reinterpret_cast<const unsigned int*>(Xb);
  float a0 = 0.f, a1 = 0.f;
  for (int pos = s0; pos < s1; ++pos) {
    int src = __builtin_amdgcn_readfirstlane(ssrc[r * EE + pos]);
    float w = sw[r * EE + pos];
    unsigned int d = Xu[(size_t)src * 64 + lane];
    union { unsigned int u; float f; } lo, hi;
    lo.u = d << 16;
    hi.u = d & 0xFFFF0000u;
    a0 += w * lo.f;
    a1 += w * hi.f;
  }
  unsigned short* P = (rr == 0) ? P0 : ((rr == 1) ? P1 : P2);
  unsigned int word = (unsigned int)f2bf(a0) | ((unsigned int)f2bf(a1) << 16);
  reinterpret_cast<unsigned int*>(P)[(size_t)n * 64 + lane] = word;
}

// ================= multi-term GEMM =================
// LDS tiles 128x128 bf16, chunk-XOR swizzle: chunk kc (16B) of row R stored at
// element (R<<7) + ((kc ^ (R&7))<<3).

__device__ __forceinline__ void stage_B(const unsigned short* __restrict__ Wt,
                                        unsigned short* __restrict__ lB, int t) {
#pragma unroll
  for (int c = 0; c < 8; ++c) {
    int g = t + 256 * c;
    int o = g >> 4, kc = g & 15;
    int4 v = *reinterpret_cast<const int4*>(Wt + (o << 7) + (kc << 3));
    *reinterpret_cast<int4*>(&lB[(o << 7) + ((kc ^ (o & 7)) << 3)]) = v;
  }
}

// stage A tile: rows row0..row0+127 (clamped to NN-1), contiguous [n][128] bf16 source
__device__ __forceinline__ void stage_A_gen(const unsigned short* __restrict__ A,
                                            unsigned short* __restrict__ lA, int t, int row0) {
#pragma unroll
  for (int c = 0; c < 8; ++c) {
    int g = t + 256 * c;
    int o = g >> 4, kc = g & 15;
    int grow = row0 + o;
    int sr = grow < NN ? grow : NN - 1;
    int4 v = *reinterpret_cast<const int4*>(A + (size_t)sr * 128 + (kc << 3));
    *reinterpret_cast<int4*>(&lA[(o << 7) + ((kc ^ (o & 7)) << 3)]) = v;
  }
}

__device__ __forceinline__ void mfma_tile(const unsigned short* __restrict__ lA,
                                          const unsigned short* __restrict__ lB,
                                          f32x4 (&acc)[2][8], int w, int l) {
  const int lrow = l & 15, kgrp = l >> 4;
#pragma unroll
  for (int ks = 0; ks < 4; ++ks) {
    int kc = ks * 4 + kgrp;
    int ra = w * 32 + lrow;
    int rb = ra + 16;
    short8 a0 = *reinterpret_cast<const short8*>(&lA[(ra << 7) + ((kc ^ (ra & 7)) << 3)]);
    short8 a1 = *reinterpret_cast<const short8*>(&lA[(rb << 7) + ((kc ^ (rb & 7)) << 3)]);
#pragma unroll
    for (int ct = 0; ct < 8; ++ct) {
      int ro = ct * 16 + lrow;
      short8 b = *reinterpret_cast<const short8*>(&lB[(ro << 7) + ((kc ^ (ro & 7)) << 3)]);
      acc[0][ct] = __builtin_amdgcn_mfma_f32_16x16x32_bf16(a0, b, acc[0][ct], 0, 0, 0);
      acc[1][ct] = __builtin_amdgcn_mfma_f32_16x16x32_bf16(a1, b, acc[1][ct], 0, 0, 0);
    }
  }
}

// out[tile] (=)|(+=) sum_{i<NT} A_i[tile] @ W_i
template <int NT>
__launch_bounds__(256, 2)
__global__ void k_gemm_multi(const unsigned short* __restrict__ A0, const unsigned short* __restrict__ W0,
                             const unsigned short* __restrict__ A1, const unsigned short* __restrict__ W1,
                             const unsigned short* __restrict__ A2, const unsigned short* __restrict__ W2,
                             const unsigned short* __restrict__ A3, const unsigned short* __restrict__ W3,
                             float* __restrict__ outp, int accum) {
  __shared__ __align__(16) unsigned short lA[128 * 128];
  __shared__ __align__(16) unsigned short lB[128 * 128];
  const int t = threadIdx.x;
  const int row0 = blockIdx.x * 128;
  const int w = t >> 6, l = t & 63;
  const int lrow = l & 15, kgrp = l >> 4;
  f32x4 acc[2][8] = {};

  const unsigned short* As[4] = {A0, A1, A2, A3};
  const unsigned short* Ws[4] = {W0, W1, W2, W3};
#pragma unroll
  for (int term = 0; term < NT; ++term) {
    if (term) __syncthreads();
    stage_A_gen(As[term], lA, t, row0);
    stage_B(Ws[term], lB, t);
    __syncthreads();
    mfma_tile(lA, lB, acc, w, l);
  }

#pragma unroll
  for (int rt = 0; rt < 2; ++rt) {
#pragma unroll
    for (int j = 0; j < 4; ++j) {
      int grow = row0 + w * 32 + rt * 16 + kgrp * 4 + j;
      if (grow < NN) {
        float* op = outp + (size_t)grow * 128 + lrow;
        if (accum) {
#pragma unroll
          for (int ct = 0; ct < 8; ++ct) op[ct * 16] += acc[rt][ct][j];
        } else {
#pragma unroll
          for (int ct = 0; ct < 8; ++ct) op[ct * 16] = acc[rt][ct][j];
        }
      }
    }
  }
}

// epilogue layer1: h_bf16 = bf16(relu(h32 + sum_r mask[r][n]*bias[r,:]))
__global__ void k_epi1(const float* __restrict__ h32, const unsigned char* __restrict__ mask,
                       const float* __restrict__ bias, unsigned short* __restrict__ hb) {
  int gid = blockIdx.x * blockDim.x + threadIdx.x;
  if (gid >= NN * 32) return;
  int n = gid >> 5, c = (gid & 31) << 2;
  float4 v = *reinterpret_cast<const float4*>(h32 + (size_t)n * 128 + c);
  float b0 = 0, b1 = 0, b2 = 0, b3 = 0;
#pragma unroll
  for (int r = 0; r < RR; ++r) {
    if (mask[(size_t)r * NN + n]) {
      const float* bp = bias + r * 128 + c;
      b0 += bp[0]; b1 += bp[1]; b2 += bp[2]; b3 += bp[3];
    }
  }
  ushort4 o;
  o.x = f2bf(fmaxf(v.x + b0, 0.f));
  o.y = f2bf(fmaxf(v.y + b1, 0.f));
  o.z = f2bf(fmaxf(v.z + b2, 0.f));
  o.w = f2bf(fmaxf(v.w + b3, 0.f));
  *reinterpret_cast<ushort4*>(hb + (size_t)n * 128 + c) = o;
}

// epilogue layer2: out += sum_r mask[r][n]*bias[r,:]  (in-place f32)
__global__ void k_epi2(float* __restrict__ out, const unsigned char* __restrict__ mask,
                       const float* __restrict__ bias) {
  int gid = blockIdx.x * blockDim.x + threadIdx.x;
  if (gid >= NN * 32) return;
  int n = gid >> 5, c = (gid & 31) << 2;
  float b0 = 0, b1 = 0, b2 = 0, b3 = 0;
  bool any = false;
#pragma unroll
  for (int r = 0; r < RR; ++r) {
    if (mask[(size_t)r * NN + n]) {
      any = true;
      const float* bp = bias + r * 128 + c;
      b0 += bp[0]; b1 += bp[1]; b2 += bp[2]; b3 += bp[3];
    }
  }
  if (any) {
    float* p = out + (size_t)n * 128 + c;
    float4 v = *reinterpret_cast<const float4*>(p);
    v.x += b0; v.y += b1; v.z += b2; v.w += b3;
    *reinterpret_cast<float4*>(p) = v;
  }
}

extern "C" void kernel_launch(void* const* d_in, const int* in_sizes, int n_in,
                              void* d_out, int out_size, void* d_ws, size_t ws_size,
                              hipStream_t stream) {
  const float* X   = (const float*)d_in[0];
  const int*   EI  = (const int*)d_in[1];
  const float* EW  = (const float*)d_in[2];
  const float* rW1 = (const float*)d_in[3];
  const float* sW1 = (const float*)d_in[4];
  const float* b1  = (const float*)d_in[5];
  const float* rW2 = (const float*)d_in[6];
  const float* sW2 = (const float*)d_in[7];
  const float* b2  = (const float*)d_in[8];
  float* out = (float*)d_out;
  char* ws = (char*)d_ws;

  size_t off = 0;
  auto take = [&](size_t sz) { char* p = ws + off; off += (sz + 255) & ~(size_t)255; return p; };
  unsigned short* Xb   = (unsigned short*)take((size_t)NN * DD * 2);
  unsigned short* hb   = (unsigned short*)take((size_t)NN * DD * 2);
  float*          h32  = (float*)take((size_t)NN * DD * 4);
  unsigned char*  mask = (unsigned char*)take((size_t)RR * NN);
  unsigned short* rW1t = (unsigned short*)take((size_t)RR * DD * DD * 2);
  unsigned short* sW1t = (unsigned short*)take((size_t)DD * DD * 2);
  unsigned short* rW2t = (unsigned short*)take((size_t)RR * DD * DD * 2);
  unsigned short* sW2t = (unsigned short*)take((size_t)DD * DD * 2);
  int*   cnt    = (int*)take((size_t)RR * PADN * 4);
  int*   start  = (int*)take((size_t)RR * NP1 * 4);
  int*   cursor = (int*)take((size_t)RR * NN * 4);
  int*   bsum   = (int*)take((size_t)RR * NB1 * 4);
  int*   boff   = (int*)take((size_t)RR * NB1 * 4);
  int*   ssrc   = (int*)take((size_t)RR * EE * 4);
  float* sw     = (float*)take((size_t)RR * EE * 4);

  // casts
  k_cast4<<<2048, 256, 0, stream>>>(X, Xb, NN * DD / 4);
  k_castT<<<(RR * DD * DD + 255) / 256, 256, 0, stream>>>(rW1, rW1t, RR * DD * DD);
  k_castT<<<(DD * DD + 255) / 256, 256, 0, stream>>>(sW1, sW1t, DD * DD);
  k_castT<<<(RR * DD * DD + 255) / 256, 256, 0, stream>>>(rW2, rW2t, RR * DD * DD);
  k_castT<<<(DD * DD + 255) / 256, 256, 0, stream>>>(sW2, sW2t, DD * DD);

  // target mask
  k_zero<<<(RR * NN / 4 + 255) / 256, 256, 0, stream>>>((unsigned int*)mask, RR * NN / 4);
  k_mask<<<dim3((EE + 255) / 256, RR), 256, 0, stream>>>(EI, mask);

  // CSR build (edges sorted by target per relation; gathered src + weight arrays)
  k_zero<<<(RR * PADN + 255) / 256, 256, 0, stream>>>((unsigned int*)cnt, RR * PADN);
  k_hist<<<dim3((EE + 255) / 256, RR), 256, 0, stream>>>(EI, cnt);
  k_scan1<<<dim3(NB1, RR), 256, 0, stream>>>(cnt, start, bsum);
  k_scan2<<<RR, 128, 0, stream>>>(bsum, boff, start);
  k_scan3<<<dim3(NB1, RR), 256, 0, stream>>>(start, boff, cursor);
  k_scatter2<<<dim3((EE + 255) / 256, RR), 256, 0, stream>>>(EI, EW, cursor, ssrc, sw);

  const int nblk = (NN + 127) / 128;  // 782
  unsigned short* outu = (unsigned short*)d_out;
  unsigned short* h32u = (unsigned short*)h32;

  // ---- layer 1: P regions = {out_lo, out_hi, hb}
  {
    unsigned short* P0 = outu;
    unsigned short* P1 = outu + (size_t)NN * DD;
    unsigned short* P2 = hb;
    // pass 0: self + r0,r1,r2
    k_preagg<<<(3 * NN + 3) / 4, 256, 0, stream>>>(Xb, ssrc, sw, start, P0, P1, P2, 0, 3);
    k_gemm_multi<4><<<nblk, 256, 0, stream>>>(Xb, sW1t, P0, rW1t, P1, rW1t + (1 << 14), P2, rW1t + (2 << 14), h32, 0);
    // pass 1: r3,r4,r5
    k_preagg<<<(3 * NN + 3) / 4, 256, 0, stream>>>(Xb, ssrc, sw, start, P0, P1, P2, 3, 3);
    k_gemm_multi<3><<<nblk, 256, 0, stream>>>(P0, rW1t + (3 << 14), P1, rW1t + (4 << 14), P2, rW1t + (5 << 14), nullptr, nullptr, h32, 1);
    // pass 2: r6,r7
    k_preagg<<<(2 * NN + 3) / 4, 256, 0, stream>>>(Xb, ssrc, sw, start, P0, P1, P2, 6, 2);
    k_gemm_multi<2><<<nblk, 256, 0, stream>>>(P0, rW1t + (6 << 14), P1, rW1t + (7 << 14), nullptr, nullptr, nullptr, nullptr, h32, 1);
  }
  k_epi1<<<(NN * 32 + 255) / 256, 256, 0, stream>>>(h32, mask, b1, hb);

  // ---- layer 2: P regions = {h32_lo, h32_hi, Xb}; source = hb
  {
    unsigned short* P0 = h32u;
    unsigned short* P1 = h32u + (size_t)NN * DD;
    unsigned short* P2 = Xb;
    k_preagg<<<(3 * NN + 3) / 4, 256, 0, stream>>>(hb, ssrc, sw, start, P0, P1, P2, 0, 3);
    k_gemm_multi<4><<<nblk, 256, 0, stream>>>(hb, sW2t, P0, rW2t, P1, rW2t + (1 << 14), P2, rW2t + (2 << 14), out, 0);
    k_preagg<<<(3 * NN + 3) / 4, 256, 0, stream>>>(hb, ssrc, sw, start, P0, P1, P2, 3, 3);
    k_gemm_multi<3><<<nblk, 256, 0, stream>>>(P0, rW2t + (3 << 14), P1, rW2t + (4 << 14), P2, rW2t + (5 << 14), nullptr, nullptr, out, 1);
    k_preagg<<<(2 * NN + 3) / 4, 256, 0, stream>>>(hb, ssrc, sw, start, P0, P1, P2, 6, 2);
    k_gemm_multi<2><<<nblk, 256, 0, stream>>>(P0, rW2t + (6 << 14), P1, rW2t + (7 << 14), nullptr, nullptr, nullptr, nullptr, out, 1);
  }
  k_epi2<<<(NN * 32 + 255) / 256, 256, 0, stream>>>(out, mask, b2);
}